// Round 4
// baseline (223.834 us; speedup 1.0000x reference)
//
#include <hip/hip_runtime.h>
#include <hip/hip_bf16.h>
#include <stdint.h>

#define D 128

using bf16x8 = __attribute__((ext_vector_type(8))) short;
using f32x4  = __attribute__((ext_vector_type(4))) float;

__device__ __forceinline__ unsigned short f2bf(float f) {
    unsigned u = __float_as_uint(f);
    u = (u + 0x7fffu + ((u >> 16) & 1u)) >> 16;   // RNE
    return (unsigned short)u;
}
__device__ __forceinline__ float bf2f(unsigned short h) {
    return __uint_as_float(((unsigned)h) << 16);
}

// 8 fp32 -> 8 bf16 via packed HW cvt (RNE)
__device__ __forceinline__ bf16x8 cvt8(float4 a, float4 b) {
    union { bf16x8 v; __hip_bfloat162 h[4]; } u;
    u.h[0] = __float22bfloat162_rn(make_float2(a.x, a.y));
    u.h[1] = __float22bfloat162_rn(make_float2(a.z, a.w));
    u.h[2] = __float22bfloat162_rn(make_float2(b.x, b.y));
    u.h[3] = __float22bfloat162_rn(make_float2(b.z, b.w));
    return u.v;
}

// ---------- prep: Wt[r][c][k] = bf16(W[r][k][c])  +  degree count ----------
__global__ __launch_bounds__(256) void prep_kernel(
    const float* __restrict__ W, unsigned short* __restrict__ Wt,
    const int* __restrict__ dst, int* __restrict__ deg, int* __restrict__ ord,
    int wtTotal, int E)
{
    int b = blockIdx.x;
    int wtBlocks = (wtTotal + 255) >> 8;
    if (b < wtBlocks) {
        int idx = b * 256 + threadIdx.x;
        if (idx < wtTotal) {
            int r = idx >> 14;            // /(D*D)
            int rem = idx & 16383;
            int k = rem >> 7, c = rem & 127;
            Wt[(r << 14) + (c << 7) + k] = f2bf(W[idx]);
        }
    } else {
        int e = (b - wtBlocks) * 256 + threadIdx.x;
        if (e < E) ord[e] = atomicAdd(&deg[dst[e]], 1);
    }
}

// ---------- Phase 1: H[r][n][c] = bf16( feat[n][:] @ W[r] ) ----------
// rel = blockIdx.y. NO LDS, NO barriers. Each wave holds all of Wt[rel]
// as 32 MFMA A-frags in VGPRs (loaded once, frag-contiguous 16 B), and
// streams 8 groups of 16 nodes; feat frags loaded straight from global
// (2x float4 -> packed cvt), prefetched one group ahead. Block covers
// 4 waves * 8 groups * 16 = 512 nodes.
__global__ __launch_bounds__(256, 2) void transform4_kernel(
    const float* __restrict__ feat, const unsigned short* __restrict__ Wt,
    unsigned short* __restrict__ H, int N)
{
    const int rel  = blockIdx.y;
    const int tid  = threadIdx.x;
    const int wave = tid >> 6, lane = tid & 63;
    const int q    = lane >> 4, mlo = lane & 15;

    // A-frags: A[m = ct*16+mlo][k = ks*32 + q*8 + j]
    bf16x8 wfrag[8][4];
    {
        const unsigned short* wb = Wt + ((size_t)rel << 14) + (size_t)mlo * 128 + q * 8;
        #pragma unroll
        for (int ct = 0; ct < 8; ++ct)
            #pragma unroll
            for (int ks = 0; ks < 4; ++ks)
                wfrag[ct][ks] = *(const bf16x8*)(wb + ct * 16 * 128 + ks * 32);
    }

    const size_t Hbase = (size_t)rel * N * D;
    int node = blockIdx.x * 512 + wave * 128 + mlo;   // group 0 of this wave

    // prefetch group 0 feat rows (clamped; unused cols masked at store)
    float4 ra[4], rb[4];
    {
        int ld = node < N ? node : N - 1;
        #pragma unroll
        for (int ks = 0; ks < 4; ++ks) {
            const float* p = feat + (size_t)ld * D + ks * 32 + q * 8;
            ra[ks] = *(const float4*)p;
            rb[ks] = *(const float4*)(p + 4);
        }
    }

    #pragma unroll
    for (int g = 0; g < 8; ++g) {
        // convert current group's feat to B-frags
        bf16x8 bfr[4];
        #pragma unroll
        for (int ks = 0; ks < 4; ++ks) bfr[ks] = cvt8(ra[ks], rb[ks]);
        const int curnode = node;

        // prefetch next group
        node += 16;
        if (g < 7) {
            int ld = node < N ? node : N - 1;
            #pragma unroll
            for (int ks = 0; ks < 4; ++ks) {
                const float* p = feat + (size_t)ld * D + ks * 32 + q * 8;
                ra[ks] = *(const float4*)p;
                rb[ks] = *(const float4*)(p + 4);
            }
        }

        // 32 MFMA: 8 independent ct chains
        f32x4 acc[8];
        #pragma unroll
        for (int ct = 0; ct < 8; ++ct) {
            acc[ct] = (f32x4){0.f, 0.f, 0.f, 0.f};
            #pragma unroll
            for (int ks = 0; ks < 4; ++ks)
                acc[ct] = __builtin_amdgcn_mfma_f32_16x16x32_bf16(
                    wfrag[ct][ks], bfr[ks], acc[ct], 0, 0, 0);
        }

        // D[m=channel][n=node]: col=mlo (node), row=q*4+rr (channel)
        if (curnode < N) {
            unsigned short* hp = H + Hbase + (size_t)curnode * D + q * 4;
            #pragma unroll
            for (int ct = 0; ct < 8; ++ct) {
                union { ushort4 s; __hip_bfloat162 h[2]; } o;
                o.h[0] = __float22bfloat162_rn(make_float2(acc[ct][0], acc[ct][1]));
                o.h[1] = __float22bfloat162_rn(make_float2(acc[ct][2], acc[ct][3]));
                *(ushort4*)(hp + ct * 16) = o.s;
            }
        }
    }
}

// ---------- CSR scan kernels ----------
__global__ __launch_bounds__(256) void k_blocksum(
    const int* __restrict__ deg, int* __restrict__ part, int N)
{
    int t = threadIdx.x, i = blockIdx.x * 256 + t;
    int v = (i < N) ? deg[i] : 0;
    #pragma unroll
    for (int o = 32; o > 0; o >>= 1) v += __shfl_down(v, o, 64);
    __shared__ int ws_[4];
    if ((t & 63) == 0) ws_[t >> 6] = v;
    __syncthreads();
    if (t == 0) part[blockIdx.x] = ws_[0] + ws_[1] + ws_[2] + ws_[3];
}

__global__ __launch_bounds__(256) void k_scanpart(int* part, int nb)
{
    __shared__ int s[256];
    int t = threadIdx.x;
    int v = (t < nb) ? part[t] : 0;
    s[t] = v;
    #pragma unroll
    for (int o = 1; o < 256; o <<= 1) {
        __syncthreads();
        int x = (t >= o) ? s[t - o] : 0;
        __syncthreads();
        s[t] += x;
    }
    if (t < nb) part[t] = s[t] - v;   // exclusive prefix of block sums
}

__global__ __launch_bounds__(256) void k_scanfinal(
    const int* __restrict__ deg, const int* __restrict__ part,
    int* __restrict__ off, int N, int E)
{
    __shared__ int s[256];
    int t = threadIdx.x, i = blockIdx.x * 256 + t;
    int v = (i < N) ? deg[i] : 0;
    s[t] = v;
    #pragma unroll
    for (int o = 1; o < 256; o <<= 1) {
        __syncthreads();
        int x = (t >= o) ? s[t - o] : 0;
        __syncthreads();
        s[t] += x;
    }
    if (i < N) off[i] = part[blockIdx.x] + s[t] - v;   // exclusive
    if (i == 0) off[N] = E;
}

__global__ __launch_bounds__(256) void k_fill(
    const int* __restrict__ dst, const int* __restrict__ et,
    const int* __restrict__ src, const int* __restrict__ off,
    const int* __restrict__ ord, unsigned int* __restrict__ sorted, int E)
{
    int e = blockIdx.x * 256 + threadIdx.x;
    if (e >= E) return;
    sorted[off[dst[e]] + ord[e]] = ((unsigned)et[e] << 16) | (unsigned)src[e];
}

// ---------- Phase 2: per-node gather; wave-cooperative edge-pack load ----------
__global__ __launch_bounds__(256) void k_gather2(
    const unsigned short* __restrict__ H, const unsigned int* __restrict__ sorted,
    const int* __restrict__ off, const float* __restrict__ feat,
    float* __restrict__ out, int N)
{
    int n = blockIdx.x * 4 + (threadIdx.x >> 6);
    if (n >= N) return;
    int lane = threadIdx.x & 63;

    float2 acc = ((const float2*)feat)[(size_t)n * 64 + lane];   // (1+eps)*h

    int j0 = __builtin_amdgcn_readfirstlane(off[n]);
    int j1 = __builtin_amdgcn_readfirstlane(off[n + 1]);
    int deg = j1 - j0;
    if (deg > 0) {
        // one vector load grabs up to 64 edge packs for the whole wave
        unsigned ep = sorted[j0 + (lane < deg ? lane : deg - 1)];
        int m = deg < 64 ? deg : 64;
        int i = 0;
        for (; i + 4 <= m; i += 4) {
            unsigned p0 = __shfl(ep, i);
            unsigned p1 = __shfl(ep, i + 1);
            unsigned p2 = __shfl(ep, i + 2);
            unsigned p3 = __shfl(ep, i + 3);
            unsigned a0 = *(const unsigned*)(H + (((size_t)(p0 >> 16) * N + (p0 & 0xffffu)) << 7) + lane * 2);
            unsigned a1 = *(const unsigned*)(H + (((size_t)(p1 >> 16) * N + (p1 & 0xffffu)) << 7) + lane * 2);
            unsigned a2 = *(const unsigned*)(H + (((size_t)(p2 >> 16) * N + (p2 & 0xffffu)) << 7) + lane * 2);
            unsigned a3 = *(const unsigned*)(H + (((size_t)(p3 >> 16) * N + (p3 & 0xffffu)) << 7) + lane * 2);
            acc.x += bf2f((unsigned short)(a0 & 0xffffu)) + bf2f((unsigned short)(a1 & 0xffffu))
                   + bf2f((unsigned short)(a2 & 0xffffu)) + bf2f((unsigned short)(a3 & 0xffffu));
            acc.y += bf2f((unsigned short)(a0 >> 16)) + bf2f((unsigned short)(a1 >> 16))
                   + bf2f((unsigned short)(a2 >> 16)) + bf2f((unsigned short)(a3 >> 16));
        }
        for (; i < m; ++i) {
            unsigned p0 = __shfl(ep, i);
            unsigned a0 = *(const unsigned*)(H + (((size_t)(p0 >> 16) * N + (p0 & 0xffffu)) << 7) + lane * 2);
            acc.x += bf2f((unsigned short)(a0 & 0xffffu));
            acc.y += bf2f((unsigned short)(a0 >> 16));
        }
        for (int j = j0 + 64; j < j1; ++j) {      // rare high-degree tail
            unsigned p0 = sorted[j];
            unsigned a0 = *(const unsigned*)(H + (((size_t)(p0 >> 16) * N + (p0 & 0xffffu)) << 7) + lane * 2);
            acc.x += bf2f((unsigned short)(a0 & 0xffffu));
            acc.y += bf2f((unsigned short)(a0 >> 16));
        }
    }
    ((float2*)out)[(size_t)n * 64 + lane] = acc;
}

// ---------- fallbacks ----------
__global__ __launch_bounds__(256) void init_kernel(
    const float* __restrict__ feat, float* __restrict__ out, int n4)
{
    int i = blockIdx.x * 256 + threadIdx.x;
    if (i < n4) ((float4*)out)[i] = ((const float4*)feat)[i];
}

__global__ __launch_bounds__(128) void edge_matvec_kernel(
    const float* __restrict__ feat, const float* __restrict__ W,
    const int* __restrict__ et, const int* __restrict__ src,
    const int* __restrict__ dst, float* __restrict__ out, int E)
{
    __shared__ float xs[D];
    int e = blockIdx.x;
    int c = threadIdx.x;
    int s = src[e], r = et[e], d = dst[e];
    xs[c] = feat[(size_t)s * D + c];
    __syncthreads();
    const float* Wr = W + (size_t)r * D * D;
    float acc = 0.f;
    #pragma unroll 8
    for (int k = 0; k < D; ++k) acc += xs[k] * Wr[(size_t)k * D + c];
    atomicAdd(out + (size_t)d * D + c, acc);
}

static inline size_t al256(size_t x) { return (x + 255) & ~(size_t)255; }

extern "C" void kernel_launch(void* const* d_in, const int* in_sizes, int n_in,
                              void* d_out, int out_size, void* d_ws, size_t ws_size,
                              hipStream_t stream) {
    const float* feat = (const float*)d_in[0];
    const float* W    = (const float*)d_in[1];
    const int*   et   = (const int*)d_in[2];
    const int*   src  = (const int*)d_in[3];
    const int*   dst  = (const int*)d_in[4];
    float* out = (float*)d_out;

    const int N = in_sizes[0] / D;
    const int R = in_sizes[1] / (D * D);
    const int E = in_sizes[2];

    // Workspace layout (same budget as round 3 — proven to fit)
    size_t hB   = al256((size_t)R * N * D * sizeof(unsigned short));
    size_t wtB  = al256((size_t)R * D * D * sizeof(unsigned short));
    size_t offB = al256((size_t)(N + 1) * sizeof(int));
    size_t degB = al256((size_t)N * sizeof(int));
    size_t ordB = al256((size_t)E * sizeof(int));
    size_t parB = al256(1024 * sizeof(int));
    size_t srtB = al256((size_t)E * sizeof(unsigned int));
    size_t need = hB + wtB + offB + degB + ordB + parB + srtB;

    const int nbScan = (N + 255) / 256;
    const bool packable = (N <= 65536) && (R <= 65536) && (nbScan <= 256);

    if (ws_size >= need && packable) {
        char* p = (char*)d_ws;
        unsigned short* H      = (unsigned short*)p;           p += hB;
        unsigned short* Wt     = (unsigned short*)p;           p += wtB;
        int*            off    = (int*)p;                      p += offB;
        int*            deg    = (int*)p;                      p += degB;
        int*            ord    = (int*)p;                      p += ordB;
        int*            part   = (int*)p;                      p += parB;
        unsigned int*   sorted = (unsigned int*)p;

        int wtTotal = R * D * D;
        int wtBlocks = (wtTotal + 255) / 256;
        int cntBlocks = (E + 255) / 256;

        hipMemsetAsync(deg, 0, (size_t)N * sizeof(int), stream);
        // Wt transpose+cast AND degree count in one dispatch
        prep_kernel<<<wtBlocks + cntBlocks, 256, 0, stream>>>(W, Wt, dst, deg, ord, wtTotal, E);

        // Phase 1: typed linear into H (barrier-free, Wt-in-registers)
        dim3 tg((N + 511) / 512, R);
        transform4_kernel<<<tg, 256, 0, stream>>>(feat, Wt, H, N);

        // CSR build (by dst)
        k_blocksum<<<nbScan, 256, 0, stream>>>(deg, part, N);
        k_scanpart<<<1, 256, 0, stream>>>(part, nbScan);
        k_scanfinal<<<nbScan, 256, 0, stream>>>(deg, part, off, N, E);
        k_fill<<<cntBlocks, 256, 0, stream>>>(dst, et, src, off, ord, sorted, E);

        // Phase 2: gather-sum per node, fused with (1+eps)*feat
        k_gather2<<<(N + 3) / 4, 256, 0, stream>>>(H, sorted, off, feat, out, N);
    } else {
        int n4 = (N * D) / 4;
        init_kernel<<<(n4 + 255) / 256, 256, 0, stream>>>(feat, out, n4);
        edge_matvec_kernel<<<E, 128, 0, stream>>>(feat, W, et, src, dst, out, E);
    }
}